// Round 14
// baseline (201.564 us; speedup 1.0000x reference)
//
#include <hip/hip_runtime.h>
#include <hip/hip_bf16.h>
#include <math.h>

using bf16 = __hip_bfloat16;

typedef __attribute__((ext_vector_type(4))) float fv4;
typedef __attribute__((ext_vector_type(4))) short sh4;
typedef __attribute__((ext_vector_type(8))) short sh8;
typedef __attribute__((ext_vector_type(4))) float f4acc;

#define T_TOK 2048
#define HD    1024
#define NE    16
#define KD    1024
#define NPAIR 8192
#define RBLK  640    // K2 routed region: 80 entries x 8 nt
#define RBLK3 1280   // K3 routed region: 80 entries x 8 nt x 2 ksplit

// ---- workspace layout (bytes); peak ~34 MB ----
static constexpr size_t OFF_XB    = 0;
static constexpr size_t OFF_GUB   = 4194304;
static constexpr size_t OFF_ACT   = 12582912;
static constexpr size_t OFF_H1    = 16777216;
static constexpr size_t OFF_TOPI  = 33554432;
static constexpr size_t OFF_TOPV  = 33587200;
static constexpr size_t OFF_PTOK  = 33619968;
static constexpr size_t OFF_PWT   = 33652736;
static constexpr size_t OFF_OFFS  = 33685504;
static constexpr size_t OFF_CNT   = 33686016;
static constexpr size_t OFF_CBASE = 33686528;
static constexpr size_t OFF_QUEUE = 33687040;

__device__ __forceinline__ short f2bf(float f) {
  __hip_bfloat16 h = __float2bfloat16(f);
  union { __hip_bfloat16 b; short s; } u; u.b = h; return u.s;
}
__device__ __forceinline__ float bf2f(short s) {
  union { unsigned u; float f; } c; c.u = ((unsigned)(unsigned short)s) << 16; return c.f;
}
__device__ __forceinline__ void async16(const void* g, void* l) {
  __builtin_amdgcn_global_load_lds(
      (const __attribute__((address_space(1))) void*)g,
      (__attribute__((address_space(3))) void*)l, 16, 0, 0);
}

// ---------- router: logits+top4 (no atomics), emits xb bf16, zeroes d_out ----------
__global__ __launch_bounds__(256) void router_kernel(const float* __restrict__ x,
                                                     const float* __restrict__ gw,
                                                     int* __restrict__ topi,
                                                     float* __restrict__ topv,
                                                     short* __restrict__ xb,
                                                     float* __restrict__ out) {
  __shared__ float gsh[NE * HD];  // 64 KiB
  const int tid = threadIdx.x;
  const int wave = tid >> 6;
  const int lane = tid & 63;
  const int t = blockIdx.x * 4 + wave;

#pragma unroll
  for (int r = 0; r < 16; ++r) {
    int idx = r * 256 + tid;
    ((fv4*)gsh)[idx] = ((const fv4*)gw)[idx];
  }

  const float* xr = x + (size_t)t * HD;
  fv4 xa[4];
#pragma unroll
  for (int q = 0; q < 4; ++q) xa[q] = *(const fv4*)(xr + q * 256 + lane * 4);

#pragma unroll
  for (int q = 0; q < 4; ++q) {
    sh4 o; o[0]=f2bf(xa[q][0]); o[1]=f2bf(xa[q][1]); o[2]=f2bf(xa[q][2]); o[3]=f2bf(xa[q][3]);
    *(sh4*)(xb + (size_t)t * HD + q * 256 + lane * 4) = o;
    *(fv4*)(out + (size_t)t * HD + q * 256 + lane * 4) = (fv4)(0.f);
  }

  __syncthreads();

  float p[NE];
#pragma unroll
  for (int e = 0; e < NE; ++e) {
    const float* g = gsh + e * HD;
    float a = 0.f;
#pragma unroll
    for (int q = 0; q < 4; ++q) {
      fv4 gv = *(const fv4*)(g + q * 256 + lane * 4);
      a += xa[q][0] * gv[0] + xa[q][1] * gv[1] + xa[q][2] * gv[2] + xa[q][3] * gv[3];
    }
    p[e] = a;
  }
#pragma unroll
  for (int off = 1; off < 64; off <<= 1) {
#pragma unroll
    for (int e = 0; e < NE; ++e) p[e] += __shfl_xor(p[e], off);
  }

  int sel_i[4]; float sel_v[4];
#pragma unroll
  for (int k = 0; k < 4; ++k) {
    float best = p[0]; int bi = 0;
#pragma unroll
    for (int e = 1; e < NE; ++e) {
      bool c = p[e] > best;
      best = c ? p[e] : best;
      bi   = c ? e : bi;
    }
    sel_i[k] = bi; sel_v[k] = best;
#pragma unroll
    for (int e = 0; e < NE; ++e) p[e] = (e == bi) ? -3.4e38f : p[e];
  }
  float m = sel_v[0];
  float e0 = expf(sel_v[0] - m), e1 = expf(sel_v[1] - m);
  float e2 = expf(sel_v[2] - m), e3 = expf(sel_v[3] - m);
  float inv = 1.f / (e0 + e1 + e2 + e3);

  if (lane == 0) {
    topi[t * 4 + 0] = sel_i[0]; topv[t * 4 + 0] = e0 * inv;
    topi[t * 4 + 1] = sel_i[1]; topv[t * 4 + 1] = e1 * inv;
    topi[t * 4 + 2] = sel_i[2]; topv[t * 4 + 2] = e2 * inv;
    topi[t * 4 + 3] = sel_i[3]; topv[t * 4 + 3] = e3 * inv;
  }
}

// ---------- parallel route build ----------
__global__ __launch_bounds__(1024) void count_kernel(const int* __restrict__ topi,
                                                     int* __restrict__ cnt) {
  const int b = blockIdx.x;
  const int wave = threadIdx.x >> 6;
  const int lane = threadIdx.x & 63;
  const int base = b * 1024;
  int c = 0;
#pragma unroll
  for (int i = 0; i < 16; ++i) {
    unsigned long long m = __ballot(topi[base + i * 64 + lane] == wave);
    c += __popcll(m);
  }
  if (lane == 0) cnt[b * NE + wave] = c;
}

__global__ void scan2_kernel(const int* __restrict__ cnt,
                             int* __restrict__ offsets,
                             int* __restrict__ cbase,
                             int* __restrict__ queue) {
  if (threadIdx.x == 0 && blockIdx.x == 0) {
    int acc = 0;
    for (int e = 0; e < NE; ++e) {
      offsets[e] = acc;
      for (int b = 0; b < 8; ++b) { cbase[b * NE + e] = acc; acc += cnt[b * NE + e]; }
    }
    offsets[NE] = acc;
    int nq = 0;
    for (int e = 0; e < NE; ++e) {
      int c = offsets[e + 1] - offsets[e];
      int mts = (c + 127) >> 7;
      for (int m = 0; m < mts; ++m) queue[1 + nq++] = (e << 8) | m;
    }
    queue[0] = nq;   // nq <= 80
  }
}

__global__ __launch_bounds__(1024) void compact_kernel(const int* __restrict__ topi,
                                                       const float* __restrict__ topv,
                                                       const int* __restrict__ cbase,
                                                       int* __restrict__ ptok,
                                                       float* __restrict__ pwt) {
  const int b = blockIdx.x;
  const int wave = threadIdx.x >> 6;
  const int lane = threadIdx.x & 63;
  const int base = b * 1024;
  int slot = cbase[b * NE + wave];
#pragma unroll
  for (int i = 0; i < 16; ++i) {
    const int p = base + i * 64 + lane;
    const bool match = (topi[p] == wave);
    unsigned long long m = __ballot(match);
    unsigned long long lt = (lane == 0) ? 0ull : ((~0ull) >> (64 - lane));
    int pre = __popcll(m & lt);
    if (match) { ptok[slot + pre] = p >> 2; pwt[slot + pre] = topv[p]; }
    slot += __popcll(m);
  }
}

// ---------- shared-expert activation ----------
__global__ __launch_bounds__(256) void act_kernel(const short* __restrict__ gub,
                                                  short* __restrict__ act) {
  int i = blockIdx.x * 256 + threadIdx.x;
  int t = i >> 8, g = i & 255;
  sh4 gs = *(const sh4*)(gub + (size_t)t * 2048 + g * 4);
  sh4 us = *(const sh4*)(gub + (size_t)t * 2048 + 1024 + g * 4);
  sh4 o;
#pragma unroll
  for (int q = 0; q < 4; ++q) {
    float gg = bf2f(gs[q]);
    float s = gg / (1.f + expf(-gg)) * bf2f(us[q]);
    o[q] = f2bf(s);
  }
  *(sh4*)(act + (size_t)t * 1024 + g * 4) = o;
}

// ---------- K2 GEMM (R13): plain 2-phase, fp32-B reg-staged, queued routed ----------
__global__ __launch_bounds__(256) void gemm_k2_kernel(
    const bf16* __restrict__ A_sh, const bf16* __restrict__ A_rt,
    const float* __restrict__ B_sh, const float* __restrict__ B_rt,
    short* __restrict__ O_sh, short* __restrict__ O_rt,
    const int* __restrict__ ptok, const float* __restrict__ pwt,
    const int* __restrict__ offsets, const int* __restrict__ queue) {
  __shared__ bf16 Ash[2][128][32];
  __shared__ bf16 Bsh[2][128][32];

  const int tid = threadIdx.x;
  const int lane = tid & 63;
  const int wave = tid >> 6;
  const int wm = wave >> 1, wn = wave & 1;

  const bool routed = (int)blockIdx.x < RBLK;
  int mt, nt, seg_start = 0, count = 0;
  const bf16* Abase;
  const float* Bpanel;
  if (routed) {
    const int entry = blockIdx.x >> 3;
    if (entry >= queue[0]) return;
    const int q = queue[1 + entry];
    const int e = q >> 8;
    mt = q & 255;
    nt = blockIdx.x & 7;
    seg_start = offsets[e];
    count = offsets[e + 1] - seg_start;
    Abase = A_rt;
    Bpanel = B_rt + ((size_t)e << 20) + (size_t)(nt * 128) * KD;
  } else {
    int sb = blockIdx.x - RBLK;
    constexpr int cpx = 256 >> 3;
    int sw = (sb & 7) * cpx + (sb >> 3);
    nt = sw >> 4; mt = sw & 15;
    count = 1 << 30;
    Abase = A_sh;
    Bpanel = B_sh + (size_t)(nt * 128) * KD;
  }

  const bf16* arow[2];
#pragma unroll
  for (int r = 0; r < 2; ++r) {
    int rowloc = r * 64 + wave * 16 + (lane >> 2);
    int grow;
    if (routed) {
      int slot = seg_start + mt * 128 + rowloc;
      if (slot > NPAIR - 1) slot = NPAIR - 1;
      grow = ptok[slot];
    } else {
      grow = mt * 128 + rowloc;
    }
    arow[r] = Abase + (size_t)grow * KD + (lane & 3) * 8;
  }

  const float* brow[4];
  int bwrow[4], bwcol[4];
#pragma unroll
  for (int r = 0; r < 4; ++r) {
    int idx = (r << 8) + tid;
    int row = idx >> 3, cg = idx & 7;
    brow[r] = Bpanel + (size_t)row * KD + (cg << 2);
    bwrow[r] = row; bwcol[r] = cg << 2;
  }

  f4acc acc[4][4];
#pragma unroll
  for (int i = 0; i < 4; ++i)
#pragma unroll
    for (int j = 0; j < 4; ++j) acc[i][j] = (f4acc)(0.f);

  {
    fv4 b0 = *(const fv4*)(brow[0]);
    fv4 b1 = *(const fv4*)(brow[1]);
    fv4 b2 = *(const fv4*)(brow[2]);
    fv4 b3 = *(const fv4*)(brow[3]);
    async16(arow[0], (void*)&Ash[0][wave * 16][0]);
    async16(arow[1], (void*)&Ash[0][64 + wave * 16][0]);
    sh4 p0; p0[0]=f2bf(b0[0]); p0[1]=f2bf(b0[1]); p0[2]=f2bf(b0[2]); p0[3]=f2bf(b0[3]);
    sh4 p1; p1[0]=f2bf(b1[0]); p1[1]=f2bf(b1[1]); p1[2]=f2bf(b1[2]); p1[3]=f2bf(b1[3]);
    sh4 p2; p2[0]=f2bf(b2[0]); p2[1]=f2bf(b2[1]); p2[2]=f2bf(b2[2]); p2[3]=f2bf(b2[3]);
    sh4 p3; p3[0]=f2bf(b3[0]); p3[1]=f2bf(b3[1]); p3[2]=f2bf(b3[2]); p3[3]=f2bf(b3[3]);
    *(sh4*)&Bsh[0][bwrow[0]][bwcol[0]] = p0;
    *(sh4*)&Bsh[0][bwrow[1]][bwcol[1]] = p1;
    *(sh4*)&Bsh[0][bwrow[2]][bwcol[2]] = p2;
    *(sh4*)&Bsh[0][bwrow[3]][bwcol[3]] = p3;
  }
  __syncthreads();

  int buf = 0;
  for (int kt = 0; kt < 32; ++kt) {
    const int k0n = (kt + 1) * 32;
    const bool has_next = (kt < 31);
    fv4 n0, n1, n2, n3;
    if (has_next) {
      async16(arow[0] + k0n, (void*)&Ash[buf ^ 1][wave * 16][0]);
      async16(arow[1] + k0n, (void*)&Ash[buf ^ 1][64 + wave * 16][0]);
      n0 = *(const fv4*)(brow[0] + k0n);
      n1 = *(const fv4*)(brow[1] + k0n);
      n2 = *(const fv4*)(brow[2] + k0n);
      n3 = *(const fv4*)(brow[3] + k0n);
    }

    sh8 fa[4], fb[4];
#pragma unroll
    for (int mi = 0; mi < 4; ++mi)
      fa[mi] = *(const sh8*)&Ash[buf][wm * 64 + mi * 16 + (lane & 15)][(lane >> 4) * 8];
#pragma unroll
    for (int ni = 0; ni < 4; ++ni)
      fb[ni] = *(const sh8*)&Bsh[buf][wn * 64 + ni * 16 + (lane & 15)][(lane >> 4) * 8];
#pragma unroll
    for (int mi = 0; mi < 4; ++mi)
#pragma unroll
      for (int ni = 0; ni < 4; ++ni)
        acc[mi][ni] = __builtin_amdgcn_mfma_f32_16x16x32_bf16(fa[mi], fb[ni], acc[mi][ni], 0, 0, 0);

    if (has_next) {
      sh4 p0; p0[0]=f2bf(n0[0]); p0[1]=f2bf(n0[1]); p0[2]=f2bf(n0[2]); p0[3]=f2bf(n0[3]);
      sh4 p1; p1[0]=f2bf(n1[0]); p1[1]=f2bf(n1[1]); p1[2]=f2bf(n1[2]); p1[3]=f2bf(n1[3]);
      sh4 p2; p2[0]=f2bf(n2[0]); p2[1]=f2bf(n2[1]); p2[2]=f2bf(n2[2]); p2[3]=f2bf(n2[3]);
      sh4 p3; p3[0]=f2bf(n3[0]); p3[1]=f2bf(n3[1]); p3[2]=f2bf(n3[2]); p3[3]=f2bf(n3[3]);
      *(sh4*)&Bsh[buf ^ 1][bwrow[0]][bwcol[0]] = p0;
      *(sh4*)&Bsh[buf ^ 1][bwrow[1]][bwcol[1]] = p1;
      *(sh4*)&Bsh[buf ^ 1][bwrow[2]][bwcol[2]] = p2;
      *(sh4*)&Bsh[buf ^ 1][bwrow[3]][bwcol[3]] = p3;
    }
    __syncthreads();
    buf ^= 1;
  }

  if (routed) {
#pragma unroll
    for (int mi = 0; mi < 4; ++mi) {
#pragma unroll
      for (int j = 0; j < 4; ++j) {
        int rloc = wm * 64 + mi * 16 + (lane >> 4) * 4 + j;
        if (mt * 128 + rloc >= count) continue;
        size_t orow = (size_t)(seg_start + mt * 128 + rloc) * 1024 + nt * 128;
#pragma unroll
        for (int ni = 0; ni < 4; ++ni) {
          int cloc = wn * 64 + ni * 16 + (lane & 15);
          float v = acc[mi][ni][j];
          float s = v / (1.f + expf(-v));
          O_rt[orow + cloc] = f2bf(s);
        }
      }
    }
  } else {
#pragma unroll
    for (int mi = 0; mi < 4; ++mi) {
#pragma unroll
      for (int j = 0; j < 4; ++j) {
        int rloc = wm * 64 + mi * 16 + (lane >> 4) * 4 + j;
        size_t orow = (size_t)(mt * 128 + rloc) * 2048 + nt * 128;
#pragma unroll
        for (int ni = 0; ni < 4; ++ni) {
          int cloc = wn * 64 + ni * 16 + (lane & 15);
          O_sh[orow + cloc] = f2bf(acc[mi][ni][j]);
        }
      }
    }
  }
}

// ---------- K3 GEMM: split-K x2, queued; atomicAdd partials into out ----------
// routed: bid 0..RBLK3-1 -> entry=bid>>4, nt=(bid>>1)&7, kh=bid&1
// shared: bid RBLK3.. -> sb: kh=sb&1, sw=sb>>1 (mt=sw>>3, nt=sw&7)
__global__ __launch_bounds__(256) void gemm_k3_kernel(
    const bf16* __restrict__ A_sh, const bf16* __restrict__ A_rt,
    const float* __restrict__ B_sh, const float* __restrict__ B_rt,
    float* __restrict__ out,
    const int* __restrict__ ptok, const float* __restrict__ pwt,
    const int* __restrict__ offsets, const int* __restrict__ queue) {
  __shared__ bf16 Ash[2][128][32];
  __shared__ bf16 Bsh[2][128][32];

  const int tid = threadIdx.x;
  const int lane = tid & 63;
  const int wave = tid >> 6;
  const int wm = wave >> 1, wn = wave & 1;

  const bool routed = (int)blockIdx.x < RBLK3;
  int mt, nt, kh, seg_start = 0, count = 0;
  const bf16* Abase;
  const float* Bpanel;
  if (routed) {
    const int entry = blockIdx.x >> 4;
    if (entry >= queue[0]) return;
    const int q = queue[1 + entry];
    const int e = q >> 8;
    mt = q & 255;
    nt = (blockIdx.x >> 1) & 7;
    kh = blockIdx.x & 1;
    seg_start = offsets[e];
    count = offsets[e + 1] - seg_start;
    Abase = A_rt;
    Bpanel = B_rt + ((size_t)e << 20) + (size_t)(nt * 128) * KD;
  } else {
    int sb = blockIdx.x - RBLK3;   // 0..255
    kh = sb & 1;
    int sw = sb >> 1;              // 0..127
    mt = sw >> 3; nt = sw & 7;
    count = 1 << 30;
    Abase = A_sh;
    Bpanel = B_sh + (size_t)(nt * 128) * KD;
  }
  const int kbase = kh * 512;      // K elements

  const bf16* arow[2];
#pragma unroll
  for (int r = 0; r < 2; ++r) {
    int rowloc = r * 64 + wave * 16 + (lane >> 2);
    int grow;
    if (routed) {
      int slot = seg_start + mt * 128 + rowloc;
      if (slot > NPAIR - 1) slot = NPAIR - 1;
      grow = slot;                 // h1 is slot-indexed
    } else {
      grow = mt * 128 + rowloc;
    }
    arow[r] = Abase + (size_t)grow * KD + (lane & 3) * 8 + kbase;
  }

  const float* brow[4];
  int bwrow[4], bwcol[4];
#pragma unroll
  for (int r = 0; r < 4; ++r) {
    int idx = (r << 8) + tid;
    int row = idx >> 3, cg = idx & 7;
    brow[r] = Bpanel + (size_t)row * KD + (cg << 2) + kbase;
    bwrow[r] = row; bwcol[r] = cg << 2;
  }

  f4acc acc[4][4];
#pragma unroll
  for (int i = 0; i < 4; ++i)
#pragma unroll
    for (int j = 0; j < 4; ++j) acc[i][j] = (f4acc)(0.f);

  {
    fv4 b0 = *(const fv4*)(brow[0]);
    fv4 b1 = *(const fv4*)(brow[1]);
    fv4 b2 = *(const fv4*)(brow[2]);
    fv4 b3 = *(const fv4*)(brow[3]);
    async16(arow[0], (void*)&Ash[0][wave * 16][0]);
    async16(arow[1], (void*)&Ash[0][64 + wave * 16][0]);
    sh4 p0; p0[0]=f2bf(b0[0]); p0[1]=f2bf(b0[1]); p0[2]=f2bf(b0[2]); p0[3]=f2bf(b0[3]);
    sh4 p1; p1[0]=f2bf(b1[0]); p1[1]=f2bf(b1[1]); p1[2]=f2bf(b1[2]); p1[3]=f2bf(b1[3]);
    sh4 p2; p2[0]=f2bf(b2[0]); p2[1]=f2bf(b2[1]); p2[2]=f2bf(b2[2]); p2[3]=f2bf(b2[3]);
    sh4 p3; p3[0]=f2bf(b3[0]); p3[1]=f2bf(b3[1]); p3[2]=f2bf(b3[2]); p3[3]=f2bf(b3[3]);
    *(sh4*)&Bsh[0][bwrow[0]][bwcol[0]] = p0;
    *(sh4*)&Bsh[0][bwrow[1]][bwcol[1]] = p1;
    *(sh4*)&Bsh[0][bwrow[2]][bwcol[2]] = p2;
    *(sh4*)&Bsh[0][bwrow[3]][bwcol[3]] = p3;
  }
  __syncthreads();

  int buf = 0;
  for (int kt = 0; kt < 16; ++kt) {
    const int k0n = (kt + 1) * 32;
    const bool has_next = (kt < 15);
    fv4 n0, n1, n2, n3;
    if (has_next) {
      async16(arow[0] + k0n, (void*)&Ash[buf ^ 1][wave * 16][0]);
      async16(arow[1] + k0n, (void*)&Ash[buf ^ 1][64 + wave * 16][0]);
      n0 = *(const fv4*)(brow[0] + k0n);
      n1 = *(const fv4*)(brow[1] + k0n);
      n2 = *(const fv4*)(brow[2] + k0n);
      n3 = *(const fv4*)(brow[3] + k0n);
    }

    sh8 fa[4], fb[4];
#pragma unroll
    for (int mi = 0; mi < 4; ++mi)
      fa[mi] = *(const sh8*)&Ash[buf][wm * 64 + mi * 16 + (lane & 15)][(lane >> 4) * 8];
#pragma unroll
    for (int ni = 0; ni < 4; ++ni)
      fb[ni] = *(const sh8*)&Bsh[buf][wn * 64 + ni * 16 + (lane & 15)][(lane >> 4) * 8];
#pragma unroll
    for (int mi = 0; mi < 4; ++mi)
#pragma unroll
      for (int ni = 0; ni < 4; ++ni)
        acc[mi][ni] = __builtin_amdgcn_mfma_f32_16x16x32_bf16(fa[mi], fb[ni], acc[mi][ni], 0, 0, 0);

    if (has_next) {
      sh4 p0; p0[0]=f2bf(n0[0]); p0[1]=f2bf(n0[1]); p0[2]=f2bf(n0[2]); p0[3]=f2bf(n0[3]);
      sh4 p1; p1[0]=f2bf(n1[0]); p1[1]=f2bf(n1[1]); p1[2]=f2bf(n1[2]); p1[3]=f2bf(n1[3]);
      sh4 p2; p2[0]=f2bf(n2[0]); p2[1]=f2bf(n2[1]); p2[2]=f2bf(n2[2]); p2[3]=f2bf(n2[3]);
      sh4 p3; p3[0]=f2bf(n3[0]); p3[1]=f2bf(n3[1]); p3[2]=f2bf(n3[2]); p3[3]=f2bf(n3[3]);
      *(sh4*)&Bsh[buf ^ 1][bwrow[0]][bwcol[0]] = p0;
      *(sh4*)&Bsh[buf ^ 1][bwrow[1]][bwcol[1]] = p1;
      *(sh4*)&Bsh[buf ^ 1][bwrow[2]][bwcol[2]] = p2;
      *(sh4*)&Bsh[buf ^ 1][bwrow[3]][bwcol[3]] = p3;
    }
    __syncthreads();
    buf ^= 1;
  }

  // epilogue: atomicAdd partial into out
  if (routed) {
#pragma unroll
    for (int mi = 0; mi < 4; ++mi) {
#pragma unroll
      for (int j = 0; j < 4; ++j) {
        int rloc = wm * 64 + mi * 16 + (lane >> 4) * 4 + j;
        if (mt * 128 + rloc >= count) continue;
        int slot = seg_start + mt * 128 + rloc;
        int token = ptok[slot];
        float w = pwt[slot];
        float* orow = out + (size_t)token * 1024 + nt * 128;
#pragma unroll
        for (int ni = 0; ni < 4; ++ni) {
          int cloc = wn * 64 + ni * 16 + (lane & 15);
          unsafeAtomicAdd(orow + cloc, w * acc[mi][ni][j]);
        }
      }
    }
  } else {
#pragma unroll
    for (int mi = 0; mi < 4; ++mi) {
#pragma unroll
      for (int j = 0; j < 4; ++j) {
        int rloc = wm * 64 + mi * 16 + (lane >> 4) * 4 + j;
        float* orow = out + (size_t)(mt * 128 + rloc) * 1024 + nt * 128;
#pragma unroll
        for (int ni = 0; ni < 4; ++ni) {
          int cloc = wn * 64 + ni * 16 + (lane & 15);
          unsafeAtomicAdd(orow + cloc, acc[mi][ni][j]);
        }
      }
    }
  }
}

extern "C" void kernel_launch(void* const* d_in, const int* in_sizes, int n_in,
                              void* d_out, int out_size, void* d_ws, size_t ws_size,
                              hipStream_t stream) {
  const float* x   = (const float*)d_in[0];
  const float* gw  = (const float*)d_in[1];
  const float* w1  = (const float*)d_in[2];
  const float* w2  = (const float*)d_in[3];
  const float* sgu = (const float*)d_in[4];
  const float* sdn = (const float*)d_in[5];
  float* out = (float*)d_out;

  char* ws = (char*)d_ws;
  bf16*  xb    = (bf16*)(ws + OFF_XB);
  bf16*  gub   = (bf16*)(ws + OFF_GUB);
  bf16*  act   = (bf16*)(ws + OFF_ACT);
  bf16*  h1    = (bf16*)(ws + OFF_H1);
  int*   topi  = (int*)(ws + OFF_TOPI);
  float* topv  = (float*)(ws + OFF_TOPV);
  int*   ptok  = (int*)(ws + OFF_PTOK);
  float* pwt   = (float*)(ws + OFF_PWT);
  int*   offs  = (int*)(ws + OFF_OFFS);
  int*   cnt   = (int*)(ws + OFF_CNT);
  int*   cbase = (int*)(ws + OFF_CBASE);
  int*   queue = (int*)(ws + OFF_QUEUE);

  router_kernel<<<512, 256, 0, stream>>>(x, gw, topi, topv, (short*)xb, out);
  count_kernel<<<8, 1024, 0, stream>>>(topi, cnt);
  scan2_kernel<<<1, 64, 0, stream>>>(cnt, offs, cbase, queue);
  compact_kernel<<<8, 1024, 0, stream>>>(topi, topv, cbase, ptok, pwt);

  // K2: routed H1 (queued, 0..639) + shared GU (640..895)
  gemm_k2_kernel<<<RBLK + 256, 256, 0, stream>>>(xb, xb, sgu, w1,
                                                 (short*)gub, (short*)h1,
                                                 ptok, pwt, offs, queue);
  act_kernel<<<2048, 256, 0, stream>>>((const short*)gub, (short*)act);

  // K3: split-K x2 routed (0..1279) + shared DOWN x2 (1280..1535); atomicAdd into out
  gemm_k3_kernel<<<RBLK3 + 256, 256, 0, stream>>>(act, h1, sdn, w2,
                                                  out, ptok, pwt, offs, queue);
}

// Round 15
// 164.907 us; speedup vs baseline: 1.2223x; 1.2223x over previous
//
#include <hip/hip_runtime.h>
#include <hip/hip_bf16.h>
#include <math.h>

using bf16 = __hip_bfloat16;

typedef __attribute__((ext_vector_type(4))) float fv4;
typedef __attribute__((ext_vector_type(4))) short sh4;
typedef __attribute__((ext_vector_type(8))) short sh8;
typedef __attribute__((ext_vector_type(4))) float f4acc;

#define T_TOK 2048
#define HD    1024
#define NE    16
#define KD    1024
#define NPAIR 8192

// ---- workspace layout (bytes); peak ~34 MB ----
static constexpr size_t OFF_XB    = 0;          // bf16 xb  [2048][1024]  4 MiB
static constexpr size_t OFF_GUB   = 4194304;    // bf16 gu  [2048][2048]  8 MiB
static constexpr size_t OFF_ACT   = 12582912;   // bf16 act [2048][1024]  4 MiB
static constexpr size_t OFF_H1    = 16777216;   // bf16 h1  [8192][1024] 16 MiB
static constexpr size_t OFF_TOPI  = 33554432;   // int  [8192]
static constexpr size_t OFF_TOPV  = 33587200;   // f32  [8192]
static constexpr size_t OFF_PTOK  = 33619968;   // int  [8192]
static constexpr size_t OFF_PWT   = 33652736;   // f32  [8192]
static constexpr size_t OFF_OFFS  = 33685504;   // int  [17]
static constexpr size_t OFF_CNT   = 33686016;   // int  [8][16]
static constexpr size_t OFF_CBASE = 33686528;   // int  [8][16]

__device__ __forceinline__ short f2bf(float f) {
  __hip_bfloat16 h = __float2bfloat16(f);
  union { __hip_bfloat16 b; short s; } u; u.b = h; return u.s;
}
__device__ __forceinline__ float bf2f(short s) {
  union { unsigned u; float f; } c; c.u = ((unsigned)(unsigned short)s) << 16; return c.f;
}
__device__ __forceinline__ void async16(const void* g, void* l) {
  __builtin_amdgcn_global_load_lds(
      (const __attribute__((address_space(1))) void*)g,
      (__attribute__((address_space(3))) void*)l, 16, 0, 0);
}

// ---------- router: logits+top4 (no atomics), emits xb bf16, zeroes d_out ----------
__global__ __launch_bounds__(256) void router_kernel(const float* __restrict__ x,
                                                     const float* __restrict__ gw,
                                                     int* __restrict__ topi,
                                                     float* __restrict__ topv,
                                                     short* __restrict__ xb,
                                                     float* __restrict__ out) {
  __shared__ float gsh[NE * HD];  // 64 KiB
  const int tid = threadIdx.x;
  const int wave = tid >> 6;
  const int lane = tid & 63;
  const int t = blockIdx.x * 4 + wave;

#pragma unroll
  for (int r = 0; r < 16; ++r) {
    int idx = r * 256 + tid;
    ((fv4*)gsh)[idx] = ((const fv4*)gw)[idx];
  }

  const float* xr = x + (size_t)t * HD;
  fv4 xa[4];
#pragma unroll
  for (int q = 0; q < 4; ++q) xa[q] = *(const fv4*)(xr + q * 256 + lane * 4);

  // by-products: bf16 x row + zero the output row (out untouched until K3)
#pragma unroll
  for (int q = 0; q < 4; ++q) {
    sh4 o; o[0]=f2bf(xa[q][0]); o[1]=f2bf(xa[q][1]); o[2]=f2bf(xa[q][2]); o[3]=f2bf(xa[q][3]);
    *(sh4*)(xb + (size_t)t * HD + q * 256 + lane * 4) = o;
    *(fv4*)(out + (size_t)t * HD + q * 256 + lane * 4) = (fv4)(0.f);
  }

  __syncthreads();

  float p[NE];
#pragma unroll
  for (int e = 0; e < NE; ++e) {
    const float* g = gsh + e * HD;
    float a = 0.f;
#pragma unroll
    for (int q = 0; q < 4; ++q) {
      fv4 gv = *(const fv4*)(g + q * 256 + lane * 4);
      a += xa[q][0] * gv[0] + xa[q][1] * gv[1] + xa[q][2] * gv[2] + xa[q][3] * gv[3];
    }
    p[e] = a;
  }
#pragma unroll
  for (int off = 1; off < 64; off <<= 1) {
#pragma unroll
    for (int e = 0; e < NE; ++e) p[e] += __shfl_xor(p[e], off);
  }

  int sel_i[4]; float sel_v[4];
#pragma unroll
  for (int k = 0; k < 4; ++k) {
    float best = p[0]; int bi = 0;
#pragma unroll
    for (int e = 1; e < NE; ++e) {
      bool c = p[e] > best;
      best = c ? p[e] : best;
      bi   = c ? e : bi;
    }
    sel_i[k] = bi; sel_v[k] = best;
#pragma unroll
    for (int e = 0; e < NE; ++e) p[e] = (e == bi) ? -3.4e38f : p[e];
  }
  float m = sel_v[0];
  float e0 = expf(sel_v[0] - m), e1 = expf(sel_v[1] - m);
  float e2 = expf(sel_v[2] - m), e3 = expf(sel_v[3] - m);
  float inv = 1.f / (e0 + e1 + e2 + e3);

  if (lane == 0) {
    topi[t * 4 + 0] = sel_i[0]; topv[t * 4 + 0] = e0 * inv;
    topi[t * 4 + 1] = sel_i[1]; topv[t * 4 + 1] = e1 * inv;
    topi[t * 4 + 2] = sel_i[2]; topv[t * 4 + 2] = e2 * inv;
    topi[t * 4 + 3] = sel_i[3]; topv[t * 4 + 3] = e3 * inv;
  }
}

// ---------- parallel route build: count (8 blk) -> scan (1) -> compact (8 blk) ----------
__global__ __launch_bounds__(1024) void count_kernel(const int* __restrict__ topi,
                                                     int* __restrict__ cnt) {
  const int b = blockIdx.x;            // chunk of 1024 pairs
  const int wave = threadIdx.x >> 6;   // == expert
  const int lane = threadIdx.x & 63;
  const int base = b * 1024;
  int c = 0;
#pragma unroll
  for (int i = 0; i < 16; ++i) {
    unsigned long long m = __ballot(topi[base + i * 64 + lane] == wave);
    c += __popcll(m);
  }
  if (lane == 0) cnt[b * NE + wave] = c;
}

__global__ void scan2_kernel(const int* __restrict__ cnt,
                             int* __restrict__ offsets,
                             int* __restrict__ cbase) {
  if (threadIdx.x == 0 && blockIdx.x == 0) {
    int acc = 0;
    for (int e = 0; e < NE; ++e) {
      offsets[e] = acc;
      for (int b = 0; b < 8; ++b) { cbase[b * NE + e] = acc; acc += cnt[b * NE + e]; }
    }
    offsets[NE] = acc;
  }
}

__global__ __launch_bounds__(1024) void compact_kernel(const int* __restrict__ topi,
                                                       const float* __restrict__ topv,
                                                       const int* __restrict__ cbase,
                                                       int* __restrict__ ptok,
                                                       float* __restrict__ pwt) {
  const int b = blockIdx.x;
  const int wave = threadIdx.x >> 6;   // == expert
  const int lane = threadIdx.x & 63;
  const int base = b * 1024;
  int slot = cbase[b * NE + wave];
#pragma unroll
  for (int i = 0; i < 16; ++i) {
    const int p = base + i * 64 + lane;
    const bool match = (topi[p] == wave);
    unsigned long long m = __ballot(match);
    unsigned long long lt = (lane == 0) ? 0ull : ((~0ull) >> (64 - lane));
    int pre = __popcll(m & lt);
    if (match) { ptok[slot + pre] = p >> 2; pwt[slot + pre] = topv[p]; }
    slot += __popcll(m);
  }
}

// ---------- shared-expert activation: act = silu(gate) * up (bf16 in/out) ----------
__global__ __launch_bounds__(256) void act_kernel(const short* __restrict__ gub,
                                                  short* __restrict__ act) {
  int i = blockIdx.x * 256 + threadIdx.x;
  int t = i >> 8, g = i & 255;
  sh4 gs = *(const sh4*)(gub + (size_t)t * 2048 + g * 4);
  sh4 us = *(const sh4*)(gub + (size_t)t * 2048 + 1024 + g * 4);
  sh4 o;
#pragma unroll
  for (int q = 0; q < 4; ++q) {
    float gg = bf2f(gs[q]);
    float s = gg / (1.f + expf(-gg)) * bf2f(us[q]);
    o[q] = f2bf(s);
  }
  *(sh4*)(act + (size_t)t * 1024 + g * 4) = o;
}

// ---------- paired GEMM (R10 body): plain 2-phase, fp32-B reg-staged ----------
// A bf16 via async16 (dbuf), B fp32 reg-staged -> cvt -> ds_write (dbuf).
// One __syncthreads per K-step; no asm waits, no swizzles.
// PHASE 0: routed H1 (A=xb gathered, B=w1, silu->h1 bf16)     [bid 0..2047]
//          + shared GU (A=xb, B=sgu N=2048, gub bf16)          [bid 2048..2303]
// PHASE 1: routed Y (A=h1, B=w2, atomicAdd weighted into out)  [bid 0..2047]
//          + shared DOWN (A=act, B=sdn, atomicAdd into out)    [bid 2048..2175]
template <int PHASE>
__global__ __launch_bounds__(256) void gemm_pair_kernel(
    const bf16* __restrict__ A_sh, const bf16* __restrict__ A_rt,
    const float* __restrict__ B_sh, const float* __restrict__ B_rt,
    void* __restrict__ O_sh, void* __restrict__ O_rt,
    const int* __restrict__ ptok, const float* __restrict__ pwt,
    const int* __restrict__ offsets) {
  __shared__ bf16 Ash[2][128][32];
  __shared__ bf16 Bsh[2][128][32];

  const int tid = threadIdx.x;
  const int lane = tid & 63;
  const int wave = tid >> 6;
  const int wm = wave >> 1, wn = wave & 1;

  const bool routed = (int)blockIdx.x < 2048;
  int mt, nt, seg_start = 0, count = 0;
  const bf16* Abase;
  const float* Bpanel;
  if (routed) {
    int bid = blockIdx.x;
    int e = bid & 15;            // expert -> XCD e%8 (w[e] L2 locality)
    int r = bid >> 4;
    mt = r >> 3; nt = r & 7;
    seg_start = offsets[e];
    count = offsets[e + 1] - seg_start;
    if (mt * 128 >= count) return;
    Abase = A_rt;
    Bpanel = B_rt + ((size_t)e << 20) + (size_t)(nt * 128) * KD;
  } else {
    int sb = blockIdx.x - 2048;
    constexpr int nwg = (PHASE == 0) ? 256 : 128;
    constexpr int cpx = nwg >> 3;
    int sw = (sb & 7) * cpx + (sb >> 3);
    nt = sw >> 4; mt = sw & 15;
    count = 1 << 30;
    Abase = A_sh;
    Bpanel = B_sh + (size_t)(nt * 128) * KD;
  }

  // A row pointers (2 async16 per wave per K-step)
  const bf16* arow[2];
#pragma unroll
  for (int r = 0; r < 2; ++r) {
    int rowloc = r * 64 + wave * 16 + (lane >> 2);
    int grow;
    if (routed) {
      int slot = seg_start + mt * 128 + rowloc;
      if (slot > NPAIR - 1) slot = NPAIR - 1;
      grow = (PHASE == 0) ? ptok[slot] : slot;
    } else {
      grow = mt * 128 + rowloc;
    }
    arow[r] = Abase + (size_t)grow * KD + (lane & 3) * 8;
  }

  // B row pointers (4 fv4/thread per K-step) + LDS write coords
  const float* brow[4];
  int bwrow[4], bwcol[4];
#pragma unroll
  for (int r = 0; r < 4; ++r) {
    int idx = (r << 8) + tid;
    int row = idx >> 3, cg = idx & 7;
    brow[r] = Bpanel + (size_t)row * KD + (cg << 2);
    bwrow[r] = row; bwcol[r] = cg << 2;
  }

  f4acc acc[4][4];
#pragma unroll
  for (int i = 0; i < 4; ++i)
#pragma unroll
    for (int j = 0; j < 4; ++j) acc[i][j] = (f4acc)(0.f);

  // ---- prologue: stage kt=0 into buf 0 ----
  {
    fv4 b0 = *(const fv4*)(brow[0]);
    fv4 b1 = *(const fv4*)(brow[1]);
    fv4 b2 = *(const fv4*)(brow[2]);
    fv4 b3 = *(const fv4*)(brow[3]);
    async16(arow[0], (void*)&Ash[0][wave * 16][0]);
    async16(arow[1], (void*)&Ash[0][64 + wave * 16][0]);
    sh4 p0; p0[0]=f2bf(b0[0]); p0[1]=f2bf(b0[1]); p0[2]=f2bf(b0[2]); p0[3]=f2bf(b0[3]);
    sh4 p1; p1[0]=f2bf(b1[0]); p1[1]=f2bf(b1[1]); p1[2]=f2bf(b1[2]); p1[3]=f2bf(b1[3]);
    sh4 p2; p2[0]=f2bf(b2[0]); p2[1]=f2bf(b2[1]); p2[2]=f2bf(b2[2]); p2[3]=f2bf(b2[3]);
    sh4 p3; p3[0]=f2bf(b3[0]); p3[1]=f2bf(b3[1]); p3[2]=f2bf(b3[2]); p3[3]=f2bf(b3[3]);
    *(sh4*)&Bsh[0][bwrow[0]][bwcol[0]] = p0;
    *(sh4*)&Bsh[0][bwrow[1]][bwcol[1]] = p1;
    *(sh4*)&Bsh[0][bwrow[2]][bwcol[2]] = p2;
    *(sh4*)&Bsh[0][bwrow[3]][bwcol[3]] = p3;
  }
  __syncthreads();

  int buf = 0;
  for (int kt = 0; kt < 32; ++kt) {
    const int k0n = (kt + 1) * 32;
    const bool has_next = (kt < 31);
    fv4 n0, n1, n2, n3;
    if (has_next) {
      async16(arow[0] + k0n, (void*)&Ash[buf ^ 1][wave * 16][0]);
      async16(arow[1] + k0n, (void*)&Ash[buf ^ 1][64 + wave * 16][0]);
      n0 = *(const fv4*)(brow[0] + k0n);
      n1 = *(const fv4*)(brow[1] + k0n);
      n2 = *(const fv4*)(brow[2] + k0n);
      n3 = *(const fv4*)(brow[3] + k0n);
    }

    sh8 fa[4], fb[4];
#pragma unroll
    for (int mi = 0; mi < 4; ++mi)
      fa[mi] = *(const sh8*)&Ash[buf][wm * 64 + mi * 16 + (lane & 15)][(lane >> 4) * 8];
#pragma unroll
    for (int ni = 0; ni < 4; ++ni)
      fb[ni] = *(const sh8*)&Bsh[buf][wn * 64 + ni * 16 + (lane & 15)][(lane >> 4) * 8];
#pragma unroll
    for (int mi = 0; mi < 4; ++mi)
#pragma unroll
      for (int ni = 0; ni < 4; ++ni)
        acc[mi][ni] = __builtin_amdgcn_mfma_f32_16x16x32_bf16(fa[mi], fb[ni], acc[mi][ni], 0, 0, 0);

    if (has_next) {
      sh4 p0; p0[0]=f2bf(n0[0]); p0[1]=f2bf(n0[1]); p0[2]=f2bf(n0[2]); p0[3]=f2bf(n0[3]);
      sh4 p1; p1[0]=f2bf(n1[0]); p1[1]=f2bf(n1[1]); p1[2]=f2bf(n1[2]); p1[3]=f2bf(n1[3]);
      sh4 p2; p2[0]=f2bf(n2[0]); p2[1]=f2bf(n2[1]); p2[2]=f2bf(n2[2]); p2[3]=f2bf(n2[3]);
      sh4 p3; p3[0]=f2bf(n3[0]); p3[1]=f2bf(n3[1]); p3[2]=f2bf(n3[2]); p3[3]=f2bf(n3[3]);
      *(sh4*)&Bsh[buf ^ 1][bwrow[0]][bwcol[0]] = p0;
      *(sh4*)&Bsh[buf ^ 1][bwrow[1]][bwcol[1]] = p1;
      *(sh4*)&Bsh[buf ^ 1][bwrow[2]][bwcol[2]] = p2;
      *(sh4*)&Bsh[buf ^ 1][bwrow[3]][bwcol[3]] = p3;
    }
    __syncthreads();
    buf ^= 1;
  }

  // epilogue: C/D layout col = lane&15, row = (lane>>4)*4 + j
  if (PHASE == 0) {
    if (routed) {
#pragma unroll
      for (int mi = 0; mi < 4; ++mi) {
#pragma unroll
        for (int j = 0; j < 4; ++j) {
          int rloc = wm * 64 + mi * 16 + (lane >> 4) * 4 + j;
          if (mt * 128 + rloc >= count) continue;
          size_t orow = (size_t)(seg_start + mt * 128 + rloc) * 1024 + nt * 128;
#pragma unroll
          for (int ni = 0; ni < 4; ++ni) {
            int cloc = wn * 64 + ni * 16 + (lane & 15);
            float v = acc[mi][ni][j];
            float s = v / (1.f + expf(-v));
            ((short*)O_rt)[orow + cloc] = f2bf(s);
          }
        }
      }
    } else {
#pragma unroll
      for (int mi = 0; mi < 4; ++mi) {
#pragma unroll
        for (int j = 0; j < 4; ++j) {
          int rloc = wm * 64 + mi * 16 + (lane >> 4) * 4 + j;
          size_t orow = (size_t)(mt * 128 + rloc) * 2048 + nt * 128;
#pragma unroll
          for (int ni = 0; ni < 4; ++ni) {
            int cloc = wn * 64 + ni * 16 + (lane & 15);
            ((short*)O_sh)[orow + cloc] = f2bf(acc[mi][ni][j]);
          }
        }
      }
    }
  } else {
    if (routed) {
#pragma unroll
      for (int mi = 0; mi < 4; ++mi) {
#pragma unroll
        for (int j = 0; j < 4; ++j) {
          int rloc = wm * 64 + mi * 16 + (lane >> 4) * 4 + j;
          if (mt * 128 + rloc >= count) continue;
          int slot = seg_start + mt * 128 + rloc;
          int token = ptok[slot];
          float w = pwt[slot];
          float* orow = (float*)O_rt + (size_t)token * 1024 + nt * 128;
#pragma unroll
          for (int ni = 0; ni < 4; ++ni) {
            int cloc = wn * 64 + ni * 16 + (lane & 15);
            unsafeAtomicAdd(orow + cloc, w * acc[mi][ni][j]);
          }
        }
      }
    } else {
#pragma unroll
      for (int mi = 0; mi < 4; ++mi) {
#pragma unroll
        for (int j = 0; j < 4; ++j) {
          int rloc = wm * 64 + mi * 16 + (lane >> 4) * 4 + j;
          float* orow = (float*)O_sh + (size_t)(mt * 128 + rloc) * 1024 + nt * 128;
#pragma unroll
          for (int ni = 0; ni < 4; ++ni) {
            int cloc = wn * 64 + ni * 16 + (lane & 15);
            unsafeAtomicAdd(orow + cloc, acc[mi][ni][j]);
          }
        }
      }
    }
  }
}

extern "C" void kernel_launch(void* const* d_in, const int* in_sizes, int n_in,
                              void* d_out, int out_size, void* d_ws, size_t ws_size,
                              hipStream_t stream) {
  const float* x   = (const float*)d_in[0];
  const float* gw  = (const float*)d_in[1];
  const float* w1  = (const float*)d_in[2];
  const float* w2  = (const float*)d_in[3];
  const float* sgu = (const float*)d_in[4];
  const float* sdn = (const float*)d_in[5];
  float* out = (float*)d_out;

  char* ws = (char*)d_ws;
  bf16*  xb    = (bf16*)(ws + OFF_XB);
  bf16*  gub   = (bf16*)(ws + OFF_GUB);
  bf16*  act   = (bf16*)(ws + OFF_ACT);
  bf16*  h1    = (bf16*)(ws + OFF_H1);
  int*   topi  = (int*)(ws + OFF_TOPI);
  float* topv  = (float*)(ws + OFF_TOPV);
  int*   ptok  = (int*)(ws + OFF_PTOK);
  float* pwt   = (float*)(ws + OFF_PWT);
  int*   offs  = (int*)(ws + OFF_OFFS);
  int*   cnt   = (int*)(ws + OFF_CNT);
  int*   cbase = (int*)(ws + OFF_CBASE);

  // router also casts x->bf16 and zeroes d_out (no separate memset/cast launches)
  router_kernel<<<512, 256, 0, stream>>>(x, gw, topi, topv, (short*)xb, out);
  count_kernel<<<8, 1024, 0, stream>>>(topi, cnt);
  scan2_kernel<<<1, 64, 0, stream>>>(cnt, offs, cbase);
  compact_kernel<<<8, 1024, 0, stream>>>(topi, topv, cbase, ptok, pwt);

  // K2: routed H1 (0..2047) + shared GU (2048..2303)
  gemm_pair_kernel<0><<<2304, 256, 0, stream>>>(xb, xb, sgu, w1,
                                                gub, h1, ptok, pwt, offs);
  act_kernel<<<2048, 256, 0, stream>>>((const short*)gub, (short*)act);

  // K3: routed Y (0..2047) + shared DOWN (2048..2175); atomicAdd into out
  gemm_pair_kernel<1><<<2176, 256, 0, stream>>>(act, h1, sdn, w2,
                                                out, out, ptok, pwt, offs);
}